// Round 16
// baseline (702.674 us; speedup 1.0000x reference)
//
#include <hip/hip_runtime.h>
#include <math.h>

#define TT 6
#define FC 24
#define KN 35
#define HW 65536
#define NPIX (TT*HW)   // 393216
#define CPB 16         // columns per block in col-FFT

// padded plane geometry: 5-halo on all sides, stride 272 (16B-chunk friendly)
#define VSTRIDE 272
#define VROWS   266
#define VPLANE  (VROWS*VSTRIDE)          // 72352 elems per plane
#define VIOFF   (5*VSTRIDE + 5)          // interior origin
#define NPLANES2 288                     // 2 comps x 144 ushort V planes
#define HALO_PER_PLANE 6816              // halo positions per plane
#define NPARTS 4                         // rg allocation
#define ADJ_PARTS 4                      // adj channel split: 6 ch/part
#define WQ_PER_LAYER (3*11*512)          // fwd B-frags: 16896 bf16/layer
#define WD_PER_LAYER (24*121*2)          // legacy slot (unused, keeps ws layout)

// adj MFMA geometry (pure-component, 64y x 32x tile, 2 slabs) -- R9 geometry
#define AC_ROWS 74                       // 64 output rows + 10 halo
#define AC_F16  56                       // f16 per staged row (112 B = 7 chunks)
#define AC_CPR  7                        // chunks per row
#define AC_CPC  (AC_ROWS*AC_CPR)         // 518 chunks per comp
#define AC_CH2  (2*AC_CPC)               // 1036 chunks per channel (both comps)
#define AC_COMP_BYTES (AC_CPC*16)        // 8288 B per comp tile
#define BFRAG_F16 512                    // one [32x16] f16 frag
#define BADJ_PER_LAYER_F16 (24*11*2*512) // 270336 f16 per layer

typedef float v2f __attribute__((ext_vector_type(2)));
typedef float v4f __attribute__((ext_vector_type(4)));
typedef short short8 __attribute__((ext_vector_type(8)));
typedef _Float16 half2_t __attribute__((ext_vector_type(2)));
typedef _Float16 half8_t __attribute__((ext_vector_type(8)));
typedef int  v4i  __attribute__((ext_vector_type(4)));
typedef v4i  v4i_u __attribute__((aligned(4)));   // 16B vector load, 4B alignment

__device__ inline float2 cmulf(float2 a, float2 b){
    return make_float2(a.x*b.x - a.y*b.y, a.x*b.y + a.y*b.x);
}

__device__ inline void gl_lds16(const void* g, void* l){
    __builtin_amdgcn_global_load_lds((const __attribute__((address_space(1))) unsigned int*)g,
                                     (__attribute__((address_space(3))) unsigned int*)l,
                                     16, 0, 0);
}

__device__ __host__ inline unsigned short f2bf(float x){
    unsigned u = __float_as_uint(x);
    unsigned r = (u + 0x7FFFu + ((u >> 16) & 1u)) >> 16;
    return (unsigned short)r;
}

// ---------------- halo zero (merged): Xpad float2 planes + Vp ushort planes -----
__global__ void halo_zero_all_kernel(float2* xpad, unsigned short* vp){
    int gid = blockIdx.x*256 + threadIdx.x;
    if (gid >= (TT + NPLANES2)*HALO_PER_PLANE) return;
    int p = gid / HALO_PER_PLANE;
    int i = gid - p*HALO_PER_PLANE;
    int row, col;
    if (i < 2720){
        row = i / 272; col = i - row*272;
        if (row >= 5) row += 256;
    } else {
        int j = i - 2720;
        row = 5 + j/16;
        col = j & 15;
        if (col >= 5) col += 256;
    }
    long off = (long)row*VSTRIDE + col;
    if (p < TT){
        xpad[(long)p*VPLANE + off] = make_float2(0.f, 0.f);
    } else {
        vp[(long)(p - TT)*VPLANE + off] = 0;
    }
}

// ---------------- reduction: sum|X|^2 and sum(mask) ----------------
__global__ void reduce_kernel(const float* xr, const float* xi, const float* mask, float* sums){
    __shared__ float s1[256], s2[256];
    int tid = threadIdx.x;
    int gid = blockIdx.x*256 + tid;
    float a = 0.f, b = 0.f;
    for (int i = gid; i < NPIX; i += gridDim.x*256) a += xr[i]*xr[i] + xi[i]*xi[i];
    for (int i = gid; i < TT*256; i += gridDim.x*256) b += mask[i];
    s1[tid]=a; s2[tid]=b; __syncthreads();
    for (int off=128; off>0; off>>=1){
        if (tid<off){ s1[tid]+=s1[tid+off]; s2[tid]+=s2[tid+off]; }
        __syncthreads();
    }
    if (tid==0){ atomicAdd(&sums[0], s1[0]); atomicAdd(&sums[1], s2[0]); }
}

// ---------------- normalize: Xks = (xr + i xi)/norm ----------------
__global__ void normalize_kernel(const float* xr, const float* xi, const float* sums, float2* Xks){
    int i = blockIdx.x*256 + threadIdx.x;
    float inv = rsqrtf(sums[0]/sums[1]);
    Xks[i] = make_float2(xr[i]*inv, xi[i]*inv);
}

// ---------------- fwd MFMA weight prepack: B-frag order, bf16 -------------------
__global__ void prepack_wfrag_kernel(const float* kr, const float* ki, unsigned short* Wq){
    int idx = blockIdx.x*256 + threadIdx.x;
    if (idx >= 8*WQ_PER_LAYER) return;
    int j    = idx & 7;
    int lane = (idx >> 3) & 63;
    int ky   = (idx >> 9) % 11;
    int nt   = (idx / (512*11)) % 3;
    int l    =  idx / (512*11*3);
    int quad = lane >> 4;
    int k    = quad*8 + j;
    int part = k >> 4;
    int kx   = k & 15;
    int n    = nt*16 + (lane & 15);
    int f    = n >> 1, comp = n & 1;
    float v = 0.f;
    if (kx <= 10){
        long wi = ((long)(l*24+f))*121 + ky*11 + kx;
        float wr = kr[wi], wim = ki[wi];
        v = (comp == 0) ? (part == 0 ? wr  : -wim)
                        : (part == 0 ? wim :  wr );
    }
    Wq[idx] = f2bf(v);
}

// ---------------- adj MFMA B-frag prepack (pure-component Toeplitz), f16 --------
__global__ void prepack_badj_kernel(const float* kr, const float* ki, unsigned short* Badj){
    int idx = blockIdx.x*256 + threadIdx.x;
    if (idx >= 8*BADJ_PER_LAYER_F16) return;
    int e    = idx & 511;
    int rest = idx >> 9;
    int comp = rest & 1;
    int ky   = (rest >> 1) % 11;
    int f    = ((rest >> 1) / 11) % 24;
    int l    =  (rest >> 1) / (11*24);
    int lane = e >> 3, j = e & 7;
    int n = lane & 15, q = lane >> 4;
    int kx = 8*q + j - n;
    float v = 0.f;
    if (kx >= 0 && kx <= 10){
        long src = (long)(l*24+f)*121 + (120 - (ky*11 + kx));
        v = comp ? ki[src] : kr[src];
    }
    _Float16 h = (_Float16)v;
    Badj[idx] = *(unsigned short*)&h;
}

// ---------------- FFT row pass (init only) ----------------
__global__ void fft_row_kernel(const float2* __restrict__ in, float2* __restrict__ out,
                               float dir, float scale){
    __shared__ float2 lds[2][256];
    __shared__ float2 tw[128];
    int tid = threadIdx.x;
    int line = tid >> 7;
    int j = tid & 127;
    if (tid < 128){
        float s, c;
        sincosf(dir * 6.283185307179586f * (float)tid / 256.0f, &s, &c);
        tw[tid] = make_float2(c, s);
    }
    long gline = (long)blockIdx.x*2 + line;
    const float2* src = in + gline*256;
    {
        float sg = (j & 1) ? -1.f : 1.f;
        float2 a = src[j];
        float2 b = src[j+128];
        lds[line][j]     = make_float2(a.x*sg, a.y*sg);
        lds[line][j+128] = make_float2(b.x*sg, b.y*sg);
    }
    __syncthreads();
    for (int s = 0; s < 8; s++){
        int half = 128 >> s;
        int pos = j & (half-1);
        int grp = j >> (7-s);
        int i0 = (grp << (8-s)) + pos;
        int i1 = i0 + half;
        float2 u = lds[line][i0], v = lds[line][i1];
        float2 w = tw[pos << s];
        lds[line][i0] = make_float2(u.x+v.x, u.y+v.y);
        float2 d = make_float2(u.x-v.x, u.y-v.y);
        lds[line][i1] = cmulf(d, w);
        __syncthreads();
    }
    float2* dst = out + gline*256;
    {
        int k = j;
        float sg = (k & 1) ? -scale : scale;
        float2 v = lds[line][__brev((unsigned)k) >> 24];
        dst[k] = make_float2(v.x*sg, v.y*sg);
        k = j + 128;
        sg = (k & 1) ? -scale : scale;
        v = lds[line][__brev((unsigned)k) >> 24];
        dst[k] = make_float2(v.x*sg, v.y*sg);
    }
}

// ---------------- FFT col pass (init only): writes Xpad (*k0), G, and Xbf -------
__global__ void fft_col_kernel(const float2* __restrict__ in, float2* __restrict__ Xpad,
                               float2* __restrict__ G, unsigned short* __restrict__ Xbf,
                               float dir, float scale, const float* k0){
    __shared__ float2 lds[256][CPB+1];
    __shared__ float2 tw[128];
    int tid = threadIdx.x;
    if (tid < 128){
        float s, c;
        sincosf(dir * 6.283185307179586f * (float)tid / 256.0f, &s, &c);
        tw[tid] = make_float2(c, s);
    }
    int t  = blockIdx.x / (256/CPB);
    int w0 = (blockIdx.x % (256/CPB)) * CPB;
    const float2* src = in + (long)t*HW;
    int c  = tid & (CPB-1);
    int h0 = tid >> 4;
    for (int i = 0; i < 16; i++){
        int h = h0 + 16*i;
        float2 v = src[h*256 + w0 + c];
        float sg = (h & 1) ? -1.f : 1.f;
        lds[h][c] = make_float2(v.x*sg, v.y*sg);
    }
    __syncthreads();
    int jb = tid >> 4;
    for (int s = 0; s < 8; s++){
        int half = 128 >> s;
        for (int i = 0; i < 8; i++){
            int j = jb + 16*i;
            int pos = j & (half-1);
            int grp = j >> (7-s);
            int i0 = (grp << (8-s)) + pos;
            int i1 = i0 + half;
            float2 u = lds[i0][c], v = lds[i1][c];
            float2 w = tw[pos << s];
            lds[i0][c] = make_float2(u.x+v.x, u.y+v.y);
            float2 d = make_float2(u.x-v.x, u.y-v.y);
            lds[i1][c] = cmulf(d, w);
        }
        __syncthreads();
    }
    float kk = *k0;
    for (int i = 0; i < 16; i++){
        int k = h0 + 16*i;
        float2 v = lds[__brev((unsigned)k) >> 24][c];
        float sg = (k & 1) ? -scale : scale;
        float2 g = make_float2(v.x*sg, v.y*sg);
        G[(long)t*HW + k*256 + w0 + c] = g;
        float2 x = make_float2(g.x*kk, g.y*kk);
        long off = VIOFF + (long)k*VSTRIDE + w0 + c;
        Xpad[(long)t*VPLANE + off] = x;
        unsigned short vr = f2bf(x.x), vi = f2bf(x.y);
        Xbf[((long)(0*6+t))*VPLANE + off]     = vr;
        Xbf[((long)(1*6+t))*VPLANE + off]     = vi;
        Xbf[((long)(2*6+t))*VPLANE + off - 1] = vr;   // shifted copy: c1[q] = X[q+1]
        Xbf[((long)(3*6+t))*VPLANE + off - 1] = vi;
    }
}

// ---------------- MFMA forward conv (1->24) + fused spline act ------------------
// 1D grid 1024, XCD-affine h-blocking: xcd = bid&7 owns h in [xcd*32, xcd*32+32).
// Hot A-set per XCD ~550 KB stays L2-resident; Vp output stores are NON-TEMPORAL
// (nt flag, no L2 allocation) so the 41 MB/layer write stream cannot evict it
// (adj consumes Vp on a different XCD mapping -> its L2 hits were ~nil anyway).
// Main loop: ky-outer / B-hoist / t-inner, __launch_bounds__(256,4).
// Epilogue: ping-pong transpose buffers.
__global__ __launch_bounds__(256, 4) void conv_fwd_mfma_kernel(
        const unsigned short* __restrict__ Xbf, const unsigned short* __restrict__ Wq,
        const float* __restrict__ knots, unsigned short* __restrict__ Vp){
    __shared__ __align__(16) unsigned short wlds[WQ_PER_LAYER];
    int tid = threadIdx.x;
    {
        int wv = tid >> 6, ln = tid & 63;
        #pragma unroll
        for (int r = 0; r < 9; r++){
            int c = r*256 + wv*64 + ln;
            if (c < 2112)
                gl_lds16(Wq + (long)c*8, (char*)wlds + (unsigned)(r*256 + wv*64)*16u);
        }
    }
    int bid = blockIdx.x;
    int xcd = bid & 7, bix = bid >> 3;    // 128 blocks per XCD
    int h  = xcd*32 + (bix >> 2);
    int w0 = (bix & 3)*64;
    int lane = tid & 63, wave = tid >> 6;
    int half = wave >> 1, parity = wave & 1;
    int quad = lane >> 4, l15 = lane & 15;
    int part = quad >> 1, kx0 = (quad & 1)*8;
    int col0 = half*32 + 2*l15 + kx0;

    __syncthreads();

    v4f D[3][6];
    #pragma unroll
    for (int nt = 0; nt < 3; nt++)
        #pragma unroll
        for (int t = 0; t < 6; t++) D[nt][t] = (v4f)(0.f);

    const short8* wl = (const short8*)wlds;
    const unsigned short* ab0 = Xbf + ((long)((parity*2 + part)*6))*VPLANE
                                    + (long)h*272 + w0 + col0;
    #pragma unroll
    for (int ky = 0; ky < 11; ky++){
        short8 b0 = wl[(0*11 + ky)*64 + lane];
        short8 b1 = wl[(1*11 + ky)*64 + lane];
        short8 b2 = wl[(2*11 + ky)*64 + lane];
        union { v4i i; short8 s; } a0, a1, a2, a3, a4, a5;
        const unsigned short* ar = ab0 + (long)ky*272;
        a0.i = *(const v4i_u*)(ar + 0L*VPLANE);
        a1.i = *(const v4i_u*)(ar + 1L*VPLANE);
        a2.i = *(const v4i_u*)(ar + 2L*VPLANE);
        a3.i = *(const v4i_u*)(ar + 3L*VPLANE);
        a4.i = *(const v4i_u*)(ar + 4L*VPLANE);
        a5.i = *(const v4i_u*)(ar + 5L*VPLANE);
        D[0][0] = __builtin_amdgcn_mfma_f32_16x16x32_bf16(a0.s, b0, D[0][0], 0, 0, 0);
        D[1][0] = __builtin_amdgcn_mfma_f32_16x16x32_bf16(a0.s, b1, D[1][0], 0, 0, 0);
        D[2][0] = __builtin_amdgcn_mfma_f32_16x16x32_bf16(a0.s, b2, D[2][0], 0, 0, 0);
        D[0][1] = __builtin_amdgcn_mfma_f32_16x16x32_bf16(a1.s, b0, D[0][1], 0, 0, 0);
        D[1][1] = __builtin_amdgcn_mfma_f32_16x16x32_bf16(a1.s, b1, D[1][1], 0, 0, 0);
        D[2][1] = __builtin_amdgcn_mfma_f32_16x16x32_bf16(a1.s, b2, D[2][1], 0, 0, 0);
        D[0][2] = __builtin_amdgcn_mfma_f32_16x16x32_bf16(a2.s, b0, D[0][2], 0, 0, 0);
        D[1][2] = __builtin_amdgcn_mfma_f32_16x16x32_bf16(a2.s, b1, D[1][2], 0, 0, 0);
        D[2][2] = __builtin_amdgcn_mfma_f32_16x16x32_bf16(a2.s, b2, D[2][2], 0, 0, 0);
        D[0][3] = __builtin_amdgcn_mfma_f32_16x16x32_bf16(a3.s, b0, D[0][3], 0, 0, 0);
        D[1][3] = __builtin_amdgcn_mfma_f32_16x16x32_bf16(a3.s, b1, D[1][3], 0, 0, 0);
        D[2][3] = __builtin_amdgcn_mfma_f32_16x16x32_bf16(a3.s, b2, D[2][3], 0, 0, 0);
        D[0][4] = __builtin_amdgcn_mfma_f32_16x16x32_bf16(a4.s, b0, D[0][4], 0, 0, 0);
        D[1][4] = __builtin_amdgcn_mfma_f32_16x16x32_bf16(a4.s, b1, D[1][4], 0, 0, 0);
        D[2][4] = __builtin_amdgcn_mfma_f32_16x16x32_bf16(a4.s, b2, D[2][4], 0, 0, 0);
        D[0][5] = __builtin_amdgcn_mfma_f32_16x16x32_bf16(a5.s, b0, D[0][5], 0, 0, 0);
        D[1][5] = __builtin_amdgcn_mfma_f32_16x16x32_bf16(a5.s, b1, D[1][5], 0, 0, 0);
        D[2][5] = __builtin_amdgcn_mfma_f32_16x16x32_bf16(a5.s, b2, D[2][5], 0, 0, 0);
    }

    float aout[3][4];
    #pragma unroll
    for (int nt = 0; nt < 3; nt++){
        int f = (nt*16 + l15) >> 1;
        #pragma unroll
        for (int r = 0; r < 4; r++){
            float s = 0.f;
            #pragma unroll
            for (int t = 0; t < 6; t++) s = fmaf(D[nt][t][r], D[nt][t][r], s);
            s += __shfl_xor(s, 1, 64);
            float act_in = sqrtf(s) * (1.0f/6.0f);
            float pos = fminf(fmaxf(act_in * 34.0f, 0.0f), 34.0f);
            int i0 = (int)pos; if (i0 > 33) i0 = 33;
            float frac = pos - (float)i0;
            float k0v = knots[i0*24 + f];
            float k1v = knots[(i0+1)*24 + f];
            aout[nt][r] = k0v*(1.0f - frac) + k1v*frac;
        }
    }

    // epilogue: ping-pong transpose (buf0 at wlds, buf1 at wlds+12800 B)
    float* tb0 = (float*)wlds;
    float* tb1 = (float*)(wlds + 6400);
    {
        #pragma unroll
        for (int nt = 0; nt < 3; nt++)
            #pragma unroll
            for (int r = 0; r < 4; r++){
                int px = half*32 + 2*(quad*4 + r) + parity;
                tb0[px*50 + nt*16 + l15] = D[nt][0][r] * aout[nt][r];
            }
    }
    __syncthreads();
    #pragma unroll
    for (int t = 0; t < 6; t++){
        float* cur = (t & 1) ? tb1 : tb0;
        float* nxt = (t & 1) ? tb0 : tb1;
        if (t + 1 < 6){
            #pragma unroll
            for (int nt = 0; nt < 3; nt++)
                #pragma unroll
                for (int r = 0; r < 4; r++){
                    int px = half*32 + 2*(quad*4 + r) + parity;
                    nxt[px*50 + nt*16 + l15] = D[nt][t+1][r] * aout[nt][r];
                }
        }
        #pragma unroll
        for (int q = 0; q < 6; q++){
            int idx = q*256 + tid;
            int f = idx >> 6, px = idx & 63;
            float2 val = *(const float2*)&cur[px*50 + 2*f];
            _Float16 hr = (_Float16)val.x;
            _Float16 hi2 = (_Float16)val.y;
            long off = (long)(t*24 + f)*VPLANE + VIOFF + (long)h*VSTRIDE + (w0 + px);
            __builtin_nontemporal_store(*(unsigned short*)&hr,  &Vp[off]);
            __builtin_nontemporal_store(*(unsigned short*)&hi2, &Vp[off + (long)144*VPLANE]);
        }
        if (t + 1 < 6) __syncthreads();
    }
}

// ---------------- adjoint conv 24->1 via MFMA f16 (pure-component) --------------
// 1D grid 768, XCD-affine swizzle (bijective 8 x 96): each XCD owns 3 z=(t,part)
// slices of Vp (~5 MB) -> halo re-reads between neighbor blocks are L2-served.
// rg output stores are NON-TEMPORAL (dc consumes rg on a different XCD mapping).
__global__ __launch_bounds__(256) void conv_adj_mfma_kernel(
        const unsigned short* __restrict__ Vp, const unsigned short* __restrict__ Badj,
        float2* __restrict__ rg){
    __shared__ __align__(16) char vt[2][2*AC_COMP_BYTES];   // 2 x 16,576 B
    int bid = blockIdx.x;
    int xcd = bid & 7, bix = bid >> 3;
    int flat = xcd*96 + bix;              // 96 blocks per XCD = 3 z-slices
    int z  = flat >> 5;                   // 32 blocks per z (4 Y x 8 X)
    int r2 = flat & 31;
    int Y0 = (r2 >> 3) * 64;
    int X0 = (r2 & 7) * 32;
    int t = z % 6, part = z / 6;          // part 0..3
    int tid = threadIdx.x;
    int w = tid >> 6, l = tid & 63;
    int f0 = part*6;

    // staging sources: 1036 chunks per channel (2 comps x 74 rows x 7)
    const unsigned short* gsrc[5];
    unsigned lofs[5];
    bool act[5];
    {
        const unsigned short* base = Vp + (long)(t*24 + f0)*VPLANE;
        #pragma unroll
        for (int r = 0; r < 5; r++){
            int s = r*256 + tid;
            act[r] = (s < AC_CH2);
            int se = (s < AC_CH2) ? s : (AC_CH2-1);
            int comp = se / AC_CPC;
            int rem  = se - comp*AC_CPC;
            int row  = rem / AC_CPR;
            int col  = rem - row*AC_CPR;
            gsrc[r] = base + (long)comp*144*VPLANE + (long)(Y0 + row)*VSTRIDE + X0 + col*8;
            lofs[r] = (unsigned)(r*256 + w*64)*16u;
        }
    }
    {   // prologue: stage channel f0 into buf 0
        #pragma unroll
        for (int r = 0; r < 5; r++)
            if (act[r]) gl_lds16(gsrc[r], &vt[0][0] + lofs[r]);
    }

    v4f Drr[2], Dii[2], Dir[2], Dri[2];
    #pragma unroll
    for (int sb = 0; sb < 2; sb++){
        Drr[sb] = (v4f)(0.f); Dii[sb] = (v4f)(0.f);
        Dir[sb] = (v4f)(0.f); Dri[sb] = (v4f)(0.f);
    }

    int m15 = l & 15, q = l >> 4;
    const unsigned short* bgl = Badj + (long)f0*(11*2*BFRAG_F16) + (unsigned)l*8;

    #pragma unroll 1
    for (int k = 0; k < 6; k++){
        int buf = k & 1;
        __syncthreads();   // drains vmcnt -> vt[buf] complete; prior readers of [buf^1] done
        if (k + 1 < 6){    // async-stage next channel into the other buffer
            #pragma unroll
            for (int r = 0; r < 5; r++){
                if (act[r]) gl_lds16(gsrc[r] + (long)VPLANE, &vt[buf^1][0] + lofs[r]);
                gsrc[r] += VPLANE;
            }
        }
        // A byte offset: (16w + m15 + ky)*112 + sb*32 + q*16 ; comp i adds AC_COMP_BYTES
        const char* va = &vt[buf][0] + (w*16 + m15)*112 + q*16;
        const unsigned short* bk = bgl + (long)k*(11*2*BFRAG_F16);
        #pragma unroll
        for (int ky = 0; ky < 11; ky++){
            union { v4i i; half8_t h; } br, bi;
            br.i = *(const v4i*)(bk + ky*(2*BFRAG_F16));
            bi.i = *(const v4i*)(bk + ky*(2*BFRAG_F16) + BFRAG_F16);
            const char* var = va + ky*112;
            #pragma unroll
            for (int sb = 0; sb < 2; sb++){
                union { v4i i; half8_t h; } ar, ai;
                ar.i = *(const v4i*)(var + sb*32);
                ai.i = *(const v4i*)(var + sb*32 + AC_COMP_BYTES);
                Drr[sb] = __builtin_amdgcn_mfma_f32_16x16x32_f16(ar.h, br.h, Drr[sb], 0, 0, 0);
                Dii[sb] = __builtin_amdgcn_mfma_f32_16x16x32_f16(ai.h, bi.h, Dii[sb], 0, 0, 0);
                Dir[sb] = __builtin_amdgcn_mfma_f32_16x16x32_f16(ai.h, br.h, Dir[sb], 0, 0, 0);
                Dri[sb] = __builtin_amdgcn_mfma_f32_16x16x32_f16(ar.h, bi.h, Dri[sb], 0, 0, 0);
            }
        }
    }

    // combine + store (non-temporal): all 16 n-cols valid per slab
    float2* out = rg + (long)part*NPIX + (long)t*HW;
    #pragma unroll
    for (int sb = 0; sb < 2; sb++){
        int x = X0 + 16*sb + m15;
        #pragma unroll
        for (int r = 0; r < 4; r++){
            int y = Y0 + w*16 + q*4 + r;
            v2f val;
            val[0] = Drr[sb][r] + Dii[sb][r];
            val[1] = Dir[sb][r] - Dri[sb][r];
            __builtin_nontemporal_store(val, (v2f*)&out[(long)y*256 + x]);
        }
    }
}

// ---------------- fused data-consistency + momentum update + bf16 mirror --------
__global__ void dc_update_kernel(float2* __restrict__ Xpad, float2* __restrict__ m,
                                 const float2* __restrict__ rg, const float2* __restrict__ G,
                                 const float* __restrict__ mask, unsigned short* __restrict__ Xbf,
                                 const float* __restrict__ alphas, const float* __restrict__ moms,
                                 int l){
    __shared__ float2 lds[2][256];
    __shared__ float2 tw[128];
    int tid = threadIdx.x;
    int line = tid >> 7;
    int j = tid & 127;
    if (tid < 128){
        float s, c;
        sincosf(6.283185307179586f * (float)tid / 256.0f, &s, &c);
        tw[tid] = make_float2(c, s);
    }
    long gl = (long)blockIdx.x*2 + line;
    int t = (int)(gl >> 8);
    int h = (int)(gl & 255);
    float2* src = Xpad + (long)t*VPLANE + VIOFF + (long)h*VSTRIDE;
    float2 xo0, xo1;
    {
        float sg = (j & 1) ? -1.f : 1.f;
        xo0 = src[j]; xo1 = src[j+128];
        lds[line][j]     = make_float2(xo0.x*sg, xo0.y*sg);
        lds[line][j+128] = make_float2(xo1.x*sg, xo1.y*sg);
    }
    __syncthreads();
    for (int s = 0; s < 8; s++){
        int half = 128 >> s;
        int pos = j & (half-1);
        int grp = j >> (7-s);
        int i0 = (grp << (8-s)) + pos;
        int i1 = i0 + half;
        float2 u = lds[line][i0], v = lds[line][i1];
        float2 w = tw[pos << s]; w.y = -w.y;
        lds[line][i0] = make_float2(u.x+v.x, u.y+v.y);
        float2 d = make_float2(u.x-v.x, u.y-v.y);
        lds[line][i1] = cmulf(d, w);
        __syncthreads();
    }
    {
        int k1 = __brev((unsigned)j) >> 24;
        int k2 = __brev((unsigned)(j+128)) >> 24;
        float mv1 = mask[t*256 + k1] * (1.0f/256.0f);
        float mv2 = mask[t*256 + k2] * (1.0f/256.0f);
        float2 a = lds[line][j], b = lds[line][j+128];
        lds[line][j]     = make_float2(a.x*mv1, a.y*mv1);
        lds[line][j+128] = make_float2(b.x*mv2, b.y*mv2);
    }
    __syncthreads();
    for (int s = 0; s < 8; s++){
        int m2 = 1 << s;
        int pos = j & (m2-1);
        int grp = j >> s;
        int i0 = (grp << (s+1)) + pos;
        int i1 = i0 + m2;
        float2 u = lds[line][i0];
        float2 v = cmulf(lds[line][i1], tw[pos << (7-s)]);
        lds[line][i0] = make_float2(u.x+v.x, u.y+v.y);
        lds[line][i1] = make_float2(u.x-v.x, u.y-v.y);
        __syncthreads();
    }
    float a  = alphas[l];
    float mu = moms[l];
    float sg = (j & 1) ? -1.f : 1.f;
    #pragma unroll
    for (int half = 0; half < 2; half++){
        int k = j + half*128;
        long idx = gl*256 + k;
        float2 d = lds[line][k];
        d = make_float2(d.x*sg, d.y*sg);
        float2 g = G[idx];
        float rx = 0.f, ry = 0.f;
        #pragma unroll
        for (int p = 0; p < ADJ_PARTS; p++){
            float2 r = rg[idx + (long)p*NPIX];
            rx += r.x; ry += r.y;
        }
        float2 grad = make_float2(fmaf(a, d.x - g.x, rx), fmaf(a, d.y - g.y, ry));
        float2 mm;
        if (l == 0){
            mm = grad;
        } else {
            float2 mv = m[idx];
            mm = make_float2(fmaf(mu, mv.x, grad.x), fmaf(mu, mv.y, grad.y));
        }
        m[idx] = mm;
        float2 xo = half ? xo1 : xo0;
        float2 nv = make_float2(xo.x - mm.x, xo.y - mm.y);
        src[k] = nv;
        long off = VIOFF + (long)h*VSTRIDE + k;
        unsigned short vr = f2bf(nv.x), vi = f2bf(nv.y);
        Xbf[((long)(0*6+t))*VPLANE + off]     = vr;
        Xbf[((long)(1*6+t))*VPLANE + off]     = vi;
        Xbf[((long)(2*6+t))*VPLANE + off - 1] = vr;
        Xbf[((long)(3*6+t))*VPLANE + off - 1] = vi;
    }
}

// ---------------- output: stack(real, imag)*norm ----------------
__global__ void output_kernel(const float2* __restrict__ Xpad, const float* __restrict__ sums,
                              float* __restrict__ out){
    int i = blockIdx.x*256 + threadIdx.x;
    int t = i >> 16;
    int p = i & 65535;
    int h = p >> 8, w = p & 255;
    float norm = sqrtf(sums[0]/sums[1]);
    float2 v = Xpad[(long)t*VPLANE + VIOFF + h*VSTRIDE + w];
    out[2*i]   = v.x * norm;
    out[2*i+1] = v.y * norm;
}

extern "C" void kernel_launch(void* const* d_in, const int* in_sizes, int n_in,
                              void* d_out, int out_size, void* d_ws, size_t ws_size,
                              hipStream_t stream){
    const float* Xr    = (const float*)d_in[0];
    const float* Xi    = (const float*)d_in[1];
    const float* mask  = (const float*)d_in[2];
    const float* kr    = (const float*)d_in[3];
    const float* ki    = (const float*)d_in[4];
    const float* knots = (const float*)d_in[5];
    const float* alph  = (const float*)d_in[6];
    const float* moms  = (const float*)d_in[7];
    const float* k0    = (const float*)d_in[8];

    float* ws   = (float*)d_ws;
    float* sums = ws;                                          // 16 floats
    unsigned int*   Wd  = (unsigned int*)(ws + 16);            // legacy slot
    unsigned short* Wq  = (unsigned short*)(Wd + 8*WD_PER_LAYER);  // 8*16896 bf16
    unsigned short* Xbf = Wq + 8*WQ_PER_LAYER;                 // 24*VPLANE bf16
    float2* mbuf = (float2*)(Xbf + 24*VPLANE);
    float2* G    = mbuf + NPIX;
    float2* rg   = G    + NPIX;                                // NPARTS*NPIX; [0] also init tmp
    float2* Xpad = rg   + NPARTS*NPIX;                         // 6*VPLANE float2
    unsigned short* Vp = (unsigned short*)(Xpad + TT*VPLANE);  // 288*VPLANE ushort (f16)
    float2* Xks  = (float2*)Vp;                                // init-only alias
    unsigned short* Badj = Vp + (size_t)NPLANES2*VPLANE;       // adj B-frags (4.3 MB)

    const float OS = 1.0f/16.0f;

    hipMemsetAsync(sums, 0, 2*sizeof(float), stream);
    hipMemsetAsync(Xbf, 0, (size_t)24*VPLANE*sizeof(unsigned short), stream);  // bf16 halos

    prepack_wfrag_kernel<<<(8*WQ_PER_LAYER + 255)/256, 256, 0, stream>>>(kr, ki, Wq);
    prepack_badj_kernel<<<(8*BADJ_PER_LAYER_F16 + 255)/256, 256, 0, stream>>>(kr, ki, Badj);
    reduce_kernel<<<384, 256, 0, stream>>>(Xr, Xi, mask, sums);
    normalize_kernel<<<NPIX/256, 256, 0, stream>>>(Xr, Xi, sums, Xks);

    // init: Xpad = k2i(Xks)*k0 (padded, + bf16 mirror) ; G = k2i(Xks)
    fft_row_kernel<<<TT*128, 256, 0, stream>>>(Xks, rg, +1.0f, OS);
    fft_col_kernel<<<TT*(256/CPB), 256, 0, stream>>>(rg, Xpad, G, Xbf, +1.0f, OS, k0);

    // zero halos AFTER init (Xks alias in Vp region is dead now)
    halo_zero_all_kernel<<<((TT+NPLANES2)*HALO_PER_PLANE + 255)/256, 256, 0, stream>>>(Xpad, Vp);

    for (int l = 0; l < 8; l++){
        conv_fwd_mfma_kernel<<<dim3(4*256,1,1), 256, 0, stream>>>(
            Xbf, Wq + (long)l*WQ_PER_LAYER, knots + (long)l*KN*FC, Vp);
        conv_adj_mfma_kernel<<<dim3(8*4*ADJ_PARTS*TT,1,1), 256, 0, stream>>>(
            Vp, Badj + (long)l*BADJ_PER_LAYER_F16, rg);
        dc_update_kernel<<<TT*128, 256, 0, stream>>>(Xpad, mbuf, rg, G, mask, Xbf, alph, moms, l);
    }

    output_kernel<<<NPIX/256, 256, 0, stream>>>(Xpad, sums, (float*)d_out);
}

// Round 17
// 597.893 us; speedup vs baseline: 1.1753x; 1.1753x over previous
//
#include <hip/hip_runtime.h>
#include <math.h>

#define TT 6
#define FC 24
#define KN 35
#define HW 65536
#define NPIX (TT*HW)   // 393216
#define CPB 16         // columns per block in col-FFT

// padded plane geometry: 5-halo on all sides, stride 272 (16B-chunk friendly)
#define VSTRIDE 272
#define VROWS   266
#define VPLANE  (VROWS*VSTRIDE)          // 72352 elems per plane
#define VIOFF   (5*VSTRIDE + 5)          // interior origin
#define NPLANES2 288                     // 2 comps x 144 ushort V planes
#define HALO_PER_PLANE 6816              // halo positions per plane
#define NPARTS 4                         // rg allocation
#define ADJ_PARTS 4                      // adj channel split: 6 ch/part
#define WQ_PER_LAYER (3*11*512)          // fwd B-frags: 16896 bf16/layer
#define WD_PER_LAYER (24*121*2)          // legacy slot (unused, keeps ws layout)

// adj MFMA geometry (pure-component, 64y x 32x tile, 2 slabs) -- R9 geometry
#define AC_ROWS 74                       // 64 output rows + 10 halo
#define AC_F16  56                       // f16 per staged row (112 B = 7 chunks)
#define AC_CPR  7                        // chunks per row
#define AC_CPC  (AC_ROWS*AC_CPR)         // 518 chunks per comp
#define AC_CH2  (2*AC_CPC)               // 1036 chunks per channel (both comps)
#define AC_COMP_BYTES (AC_CPC*16)        // 8288 B per comp tile
#define BFRAG_F16 512                    // one [32x16] f16 frag
#define BADJ_PER_LAYER_F16 (24*11*2*512) // 270336 f16 per layer

typedef float v2f __attribute__((ext_vector_type(2)));
typedef float v4f __attribute__((ext_vector_type(4)));
typedef short short8 __attribute__((ext_vector_type(8)));
typedef _Float16 half2_t __attribute__((ext_vector_type(2)));
typedef _Float16 half8_t __attribute__((ext_vector_type(8)));
typedef int  v4i  __attribute__((ext_vector_type(4)));
typedef v4i  v4i_u __attribute__((aligned(4)));   // 16B vector load, 4B alignment

__device__ inline float2 cmulf(float2 a, float2 b){
    return make_float2(a.x*b.x - a.y*b.y, a.x*b.y + a.y*b.x);
}

__device__ inline void gl_lds16(const void* g, void* l){
    __builtin_amdgcn_global_load_lds((const __attribute__((address_space(1))) unsigned int*)g,
                                     (__attribute__((address_space(3))) unsigned int*)l,
                                     16, 0, 0);
}

__device__ __host__ inline unsigned short f2bf(float x){
    unsigned u = __float_as_uint(x);
    unsigned r = (u + 0x7FFFu + ((u >> 16) & 1u)) >> 16;
    return (unsigned short)r;
}

// ---------------- halo zero (merged): Xpad float2 planes + Vp ushort planes -----
__global__ void halo_zero_all_kernel(float2* xpad, unsigned short* vp){
    int gid = blockIdx.x*256 + threadIdx.x;
    if (gid >= (TT + NPLANES2)*HALO_PER_PLANE) return;
    int p = gid / HALO_PER_PLANE;
    int i = gid - p*HALO_PER_PLANE;
    int row, col;
    if (i < 2720){
        row = i / 272; col = i - row*272;
        if (row >= 5) row += 256;
    } else {
        int j = i - 2720;
        row = 5 + j/16;
        col = j & 15;
        if (col >= 5) col += 256;
    }
    long off = (long)row*VSTRIDE + col;
    if (p < TT){
        xpad[(long)p*VPLANE + off] = make_float2(0.f, 0.f);
    } else {
        vp[(long)(p - TT)*VPLANE + off] = 0;
    }
}

// ---------------- reduction: sum|X|^2 and sum(mask) ----------------
__global__ void reduce_kernel(const float* xr, const float* xi, const float* mask, float* sums){
    __shared__ float s1[256], s2[256];
    int tid = threadIdx.x;
    int gid = blockIdx.x*256 + tid;
    float a = 0.f, b = 0.f;
    for (int i = gid; i < NPIX; i += gridDim.x*256) a += xr[i]*xr[i] + xi[i]*xi[i];
    for (int i = gid; i < TT*256; i += gridDim.x*256) b += mask[i];
    s1[tid]=a; s2[tid]=b; __syncthreads();
    for (int off=128; off>0; off>>=1){
        if (tid<off){ s1[tid]+=s1[tid+off]; s2[tid]+=s2[tid+off]; }
        __syncthreads();
    }
    if (tid==0){ atomicAdd(&sums[0], s1[0]); atomicAdd(&sums[1], s2[0]); }
}

// ---------------- normalize: Xks = (xr + i xi)/norm ----------------
__global__ void normalize_kernel(const float* xr, const float* xi, const float* sums, float2* Xks){
    int i = blockIdx.x*256 + threadIdx.x;
    float inv = rsqrtf(sums[0]/sums[1]);
    Xks[i] = make_float2(xr[i]*inv, xi[i]*inv);
}

// ---------------- fwd MFMA weight prepack: B-frag order, bf16 -------------------
__global__ void prepack_wfrag_kernel(const float* kr, const float* ki, unsigned short* Wq){
    int idx = blockIdx.x*256 + threadIdx.x;
    if (idx >= 8*WQ_PER_LAYER) return;
    int j    = idx & 7;
    int lane = (idx >> 3) & 63;
    int ky   = (idx >> 9) % 11;
    int nt   = (idx / (512*11)) % 3;
    int l    =  idx / (512*11*3);
    int quad = lane >> 4;
    int k    = quad*8 + j;
    int part = k >> 4;
    int kx   = k & 15;
    int n    = nt*16 + (lane & 15);
    int f    = n >> 1, comp = n & 1;
    float v = 0.f;
    if (kx <= 10){
        long wi = ((long)(l*24+f))*121 + ky*11 + kx;
        float wr = kr[wi], wim = ki[wi];
        v = (comp == 0) ? (part == 0 ? wr  : -wim)
                        : (part == 0 ? wim :  wr );
    }
    Wq[idx] = f2bf(v);
}

// ---------------- adj MFMA B-frag prepack (pure-component Toeplitz), f16 --------
__global__ void prepack_badj_kernel(const float* kr, const float* ki, unsigned short* Badj){
    int idx = blockIdx.x*256 + threadIdx.x;
    if (idx >= 8*BADJ_PER_LAYER_F16) return;
    int e    = idx & 511;
    int rest = idx >> 9;
    int comp = rest & 1;
    int ky   = (rest >> 1) % 11;
    int f    = ((rest >> 1) / 11) % 24;
    int l    =  (rest >> 1) / (11*24);
    int lane = e >> 3, j = e & 7;
    int n = lane & 15, q = lane >> 4;
    int kx = 8*q + j - n;
    float v = 0.f;
    if (kx >= 0 && kx <= 10){
        long src = (long)(l*24+f)*121 + (120 - (ky*11 + kx));
        v = comp ? ki[src] : kr[src];
    }
    _Float16 h = (_Float16)v;
    Badj[idx] = *(unsigned short*)&h;
}

// ---------------- FFT row pass (init only) ----------------
__global__ void fft_row_kernel(const float2* __restrict__ in, float2* __restrict__ out,
                               float dir, float scale){
    __shared__ float2 lds[2][256];
    __shared__ float2 tw[128];
    int tid = threadIdx.x;
    int line = tid >> 7;
    int j = tid & 127;
    if (tid < 128){
        float s, c;
        sincosf(dir * 6.283185307179586f * (float)tid / 256.0f, &s, &c);
        tw[tid] = make_float2(c, s);
    }
    long gline = (long)blockIdx.x*2 + line;
    const float2* src = in + gline*256;
    {
        float sg = (j & 1) ? -1.f : 1.f;
        float2 a = src[j];
        float2 b = src[j+128];
        lds[line][j]     = make_float2(a.x*sg, a.y*sg);
        lds[line][j+128] = make_float2(b.x*sg, b.y*sg);
    }
    __syncthreads();
    for (int s = 0; s < 8; s++){
        int half = 128 >> s;
        int pos = j & (half-1);
        int grp = j >> (7-s);
        int i0 = (grp << (8-s)) + pos;
        int i1 = i0 + half;
        float2 u = lds[line][i0], v = lds[line][i1];
        float2 w = tw[pos << s];
        lds[line][i0] = make_float2(u.x+v.x, u.y+v.y);
        float2 d = make_float2(u.x-v.x, u.y-v.y);
        lds[line][i1] = cmulf(d, w);
        __syncthreads();
    }
    float2* dst = out + gline*256;
    {
        int k = j;
        float sg = (k & 1) ? -scale : scale;
        float2 v = lds[line][__brev((unsigned)k) >> 24];
        dst[k] = make_float2(v.x*sg, v.y*sg);
        k = j + 128;
        sg = (k & 1) ? -scale : scale;
        v = lds[line][__brev((unsigned)k) >> 24];
        dst[k] = make_float2(v.x*sg, v.y*sg);
    }
}

// ---------------- FFT col pass (init only): writes Xpad (*k0), G, and Xbf -------
__global__ void fft_col_kernel(const float2* __restrict__ in, float2* __restrict__ Xpad,
                               float2* __restrict__ G, unsigned short* __restrict__ Xbf,
                               float dir, float scale, const float* k0){
    __shared__ float2 lds[256][CPB+1];
    __shared__ float2 tw[128];
    int tid = threadIdx.x;
    if (tid < 128){
        float s, c;
        sincosf(dir * 6.283185307179586f * (float)tid / 256.0f, &s, &c);
        tw[tid] = make_float2(c, s);
    }
    int t  = blockIdx.x / (256/CPB);
    int w0 = (blockIdx.x % (256/CPB)) * CPB;
    const float2* src = in + (long)t*HW;
    int c  = tid & (CPB-1);
    int h0 = tid >> 4;
    for (int i = 0; i < 16; i++){
        int h = h0 + 16*i;
        float2 v = src[h*256 + w0 + c];
        float sg = (h & 1) ? -1.f : 1.f;
        lds[h][c] = make_float2(v.x*sg, v.y*sg);
    }
    __syncthreads();
    int jb = tid >> 4;
    for (int s = 0; s < 8; s++){
        int half = 128 >> s;
        for (int i = 0; i < 8; i++){
            int j = jb + 16*i;
            int pos = j & (half-1);
            int grp = j >> (7-s);
            int i0 = (grp << (8-s)) + pos;
            int i1 = i0 + half;
            float2 u = lds[i0][c], v = lds[i1][c];
            float2 w = tw[pos << s];
            lds[i0][c] = make_float2(u.x+v.x, u.y+v.y);
            float2 d = make_float2(u.x-v.x, u.y-v.y);
            lds[i1][c] = cmulf(d, w);
        }
        __syncthreads();
    }
    float kk = *k0;
    for (int i = 0; i < 16; i++){
        int k = h0 + 16*i;
        float2 v = lds[__brev((unsigned)k) >> 24][c];
        float sg = (k & 1) ? -scale : scale;
        float2 g = make_float2(v.x*sg, v.y*sg);
        G[(long)t*HW + k*256 + w0 + c] = g;
        float2 x = make_float2(g.x*kk, g.y*kk);
        long off = VIOFF + (long)k*VSTRIDE + w0 + c;
        Xpad[(long)t*VPLANE + off] = x;
        unsigned short vr = f2bf(x.x), vi = f2bf(x.y);
        Xbf[((long)(0*6+t))*VPLANE + off]     = vr;
        Xbf[((long)(1*6+t))*VPLANE + off]     = vi;
        Xbf[((long)(2*6+t))*VPLANE + off - 1] = vr;   // shifted copy: c1[q] = X[q+1]
        Xbf[((long)(3*6+t))*VPLANE + off - 1] = vi;
    }
}

// ---------------- MFMA forward conv (1->24) + fused spline act ------------------
// 1D grid 1024, XCD-affine h-blocking: xcd = bid&7 owns h in [xcd*32, xcd*32+32)
// (128 blocks = 32 h x 4 w-quadrants).  Hot A-set per XCD: 24 planes x 42 rows
// ~ 550 KB -- survives the Vp write stream in the 4 MB L2.
// Main loop: ky-outer / B-hoist / t-inner, __launch_bounds__(256,4) pins
// VGPR<=128.  Epilogue: ping-pong transpose buffers.
__global__ __launch_bounds__(256, 4) void conv_fwd_mfma_kernel(
        const unsigned short* __restrict__ Xbf, const unsigned short* __restrict__ Wq,
        const float* __restrict__ knots, unsigned short* __restrict__ Vp){
    __shared__ __align__(16) unsigned short wlds[WQ_PER_LAYER];
    int tid = threadIdx.x;
    {
        int wv = tid >> 6, ln = tid & 63;
        #pragma unroll
        for (int r = 0; r < 9; r++){
            int c = r*256 + wv*64 + ln;
            if (c < 2112)
                gl_lds16(Wq + (long)c*8, (char*)wlds + (unsigned)(r*256 + wv*64)*16u);
        }
    }
    int bid = blockIdx.x;
    int xcd = bid & 7, bix = bid >> 3;    // 128 blocks per XCD
    int h  = xcd*32 + (bix >> 2);
    int w0 = (bix & 3)*64;
    int lane = tid & 63, wave = tid >> 6;
    int half = wave >> 1, parity = wave & 1;
    int quad = lane >> 4, l15 = lane & 15;
    int part = quad >> 1, kx0 = (quad & 1)*8;
    int col0 = half*32 + 2*l15 + kx0;

    __syncthreads();

    v4f D[3][6];
    #pragma unroll
    for (int nt = 0; nt < 3; nt++)
        #pragma unroll
        for (int t = 0; t < 6; t++) D[nt][t] = (v4f)(0.f);

    const short8* wl = (const short8*)wlds;
    const unsigned short* ab0 = Xbf + ((long)((parity*2 + part)*6))*VPLANE
                                    + (long)h*272 + w0 + col0;
    #pragma unroll
    for (int ky = 0; ky < 11; ky++){
        short8 b0 = wl[(0*11 + ky)*64 + lane];
        short8 b1 = wl[(1*11 + ky)*64 + lane];
        short8 b2 = wl[(2*11 + ky)*64 + lane];
        union { v4i i; short8 s; } a0, a1, a2, a3, a4, a5;
        const unsigned short* ar = ab0 + (long)ky*272;
        a0.i = *(const v4i_u*)(ar + 0L*VPLANE);
        a1.i = *(const v4i_u*)(ar + 1L*VPLANE);
        a2.i = *(const v4i_u*)(ar + 2L*VPLANE);
        a3.i = *(const v4i_u*)(ar + 3L*VPLANE);
        a4.i = *(const v4i_u*)(ar + 4L*VPLANE);
        a5.i = *(const v4i_u*)(ar + 5L*VPLANE);
        D[0][0] = __builtin_amdgcn_mfma_f32_16x16x32_bf16(a0.s, b0, D[0][0], 0, 0, 0);
        D[1][0] = __builtin_amdgcn_mfma_f32_16x16x32_bf16(a0.s, b1, D[1][0], 0, 0, 0);
        D[2][0] = __builtin_amdgcn_mfma_f32_16x16x32_bf16(a0.s, b2, D[2][0], 0, 0, 0);
        D[0][1] = __builtin_amdgcn_mfma_f32_16x16x32_bf16(a1.s, b0, D[0][1], 0, 0, 0);
        D[1][1] = __builtin_amdgcn_mfma_f32_16x16x32_bf16(a1.s, b1, D[1][1], 0, 0, 0);
        D[2][1] = __builtin_amdgcn_mfma_f32_16x16x32_bf16(a1.s, b2, D[2][1], 0, 0, 0);
        D[0][2] = __builtin_amdgcn_mfma_f32_16x16x32_bf16(a2.s, b0, D[0][2], 0, 0, 0);
        D[1][2] = __builtin_amdgcn_mfma_f32_16x16x32_bf16(a2.s, b1, D[1][2], 0, 0, 0);
        D[2][2] = __builtin_amdgcn_mfma_f32_16x16x32_bf16(a2.s, b2, D[2][2], 0, 0, 0);
        D[0][3] = __builtin_amdgcn_mfma_f32_16x16x32_bf16(a3.s, b0, D[0][3], 0, 0, 0);
        D[1][3] = __builtin_amdgcn_mfma_f32_16x16x32_bf16(a3.s, b1, D[1][3], 0, 0, 0);
        D[2][3] = __builtin_amdgcn_mfma_f32_16x16x32_bf16(a3.s, b2, D[2][3], 0, 0, 0);
        D[0][4] = __builtin_amdgcn_mfma_f32_16x16x32_bf16(a4.s, b0, D[0][4], 0, 0, 0);
        D[1][4] = __builtin_amdgcn_mfma_f32_16x16x32_bf16(a4.s, b1, D[1][4], 0, 0, 0);
        D[2][4] = __builtin_amdgcn_mfma_f32_16x16x32_bf16(a4.s, b2, D[2][4], 0, 0, 0);
        D[0][5] = __builtin_amdgcn_mfma_f32_16x16x32_bf16(a5.s, b0, D[0][5], 0, 0, 0);
        D[1][5] = __builtin_amdgcn_mfma_f32_16x16x32_bf16(a5.s, b1, D[1][5], 0, 0, 0);
        D[2][5] = __builtin_amdgcn_mfma_f32_16x16x32_bf16(a5.s, b2, D[2][5], 0, 0, 0);
    }

    float aout[3][4];
    #pragma unroll
    for (int nt = 0; nt < 3; nt++){
        int f = (nt*16 + l15) >> 1;
        #pragma unroll
        for (int r = 0; r < 4; r++){
            float s = 0.f;
            #pragma unroll
            for (int t = 0; t < 6; t++) s = fmaf(D[nt][t][r], D[nt][t][r], s);
            s += __shfl_xor(s, 1, 64);
            float act_in = sqrtf(s) * (1.0f/6.0f);
            float pos = fminf(fmaxf(act_in * 34.0f, 0.0f), 34.0f);
            int i0 = (int)pos; if (i0 > 33) i0 = 33;
            float frac = pos - (float)i0;
            float k0v = knots[i0*24 + f];
            float k1v = knots[(i0+1)*24 + f];
            aout[nt][r] = k0v*(1.0f - frac) + k1v*frac;
        }
    }

    // epilogue: ping-pong transpose (buf0 at wlds, buf1 at wlds+12800 B)
    float* tb0 = (float*)wlds;
    float* tb1 = (float*)(wlds + 6400);
    {
        #pragma unroll
        for (int nt = 0; nt < 3; nt++)
            #pragma unroll
            for (int r = 0; r < 4; r++){
                int px = half*32 + 2*(quad*4 + r) + parity;
                tb0[px*50 + nt*16 + l15] = D[nt][0][r] * aout[nt][r];
            }
    }
    __syncthreads();
    #pragma unroll
    for (int t = 0; t < 6; t++){
        float* cur = (t & 1) ? tb1 : tb0;
        float* nxt = (t & 1) ? tb0 : tb1;
        if (t + 1 < 6){
            #pragma unroll
            for (int nt = 0; nt < 3; nt++)
                #pragma unroll
                for (int r = 0; r < 4; r++){
                    int px = half*32 + 2*(quad*4 + r) + parity;
                    nxt[px*50 + nt*16 + l15] = D[nt][t+1][r] * aout[nt][r];
                }
        }
        #pragma unroll
        for (int q = 0; q < 6; q++){
            int idx = q*256 + tid;
            int f = idx >> 6, px = idx & 63;
            float2 val = *(const float2*)&cur[px*50 + 2*f];
            _Float16 hr = (_Float16)val.x;
            _Float16 hi2 = (_Float16)val.y;
            long off = (long)(t*24 + f)*VPLANE + VIOFF + (long)h*VSTRIDE + (w0 + px);
            Vp[off] = *(unsigned short*)&hr;
            Vp[off + (long)144*VPLANE] = *(unsigned short*)&hi2;
        }
        if (t + 1 < 6) __syncthreads();
    }
}

// ---------------- adjoint conv 24->1 via MFMA f16 (pure-component) --------------
// 1D grid 768, XCD-affine swizzle (bijective 8 x 96): each XCD owns 3 z=(t,part)
// slices of Vp (~5 MB) -> halo re-reads between neighbor blocks are L2-served.
__global__ __launch_bounds__(256) void conv_adj_mfma_kernel(
        const unsigned short* __restrict__ Vp, const unsigned short* __restrict__ Badj,
        float2* __restrict__ rg){
    __shared__ __align__(16) char vt[2][2*AC_COMP_BYTES];   // 2 x 16,576 B
    int bid = blockIdx.x;
    int xcd = bid & 7, bix = bid >> 3;
    int flat = xcd*96 + bix;              // 96 blocks per XCD = 3 z-slices
    int z  = flat >> 5;                   // 32 blocks per z (4 Y x 8 X)
    int r2 = flat & 31;
    int Y0 = (r2 >> 3) * 64;
    int X0 = (r2 & 7) * 32;
    int t = z % 6, part = z / 6;          // part 0..3
    int tid = threadIdx.x;
    int w = tid >> 6, l = tid & 63;
    int f0 = part*6;

    // staging sources: 1036 chunks per channel (2 comps x 74 rows x 7)
    const unsigned short* gsrc[5];
    unsigned lofs[5];
    bool act[5];
    {
        const unsigned short* base = Vp + (long)(t*24 + f0)*VPLANE;
        #pragma unroll
        for (int r = 0; r < 5; r++){
            int s = r*256 + tid;
            act[r] = (s < AC_CH2);
            int se = (s < AC_CH2) ? s : (AC_CH2-1);
            int comp = se / AC_CPC;
            int rem  = se - comp*AC_CPC;
            int row  = rem / AC_CPR;
            int col  = rem - row*AC_CPR;
            gsrc[r] = base + (long)comp*144*VPLANE + (long)(Y0 + row)*VSTRIDE + X0 + col*8;
            lofs[r] = (unsigned)(r*256 + w*64)*16u;
        }
    }
    {   // prologue: stage channel f0 into buf 0
        #pragma unroll
        for (int r = 0; r < 5; r++)
            if (act[r]) gl_lds16(gsrc[r], &vt[0][0] + lofs[r]);
    }

    v4f Drr[2], Dii[2], Dir[2], Dri[2];
    #pragma unroll
    for (int sb = 0; sb < 2; sb++){
        Drr[sb] = (v4f)(0.f); Dii[sb] = (v4f)(0.f);
        Dir[sb] = (v4f)(0.f); Dri[sb] = (v4f)(0.f);
    }

    int m15 = l & 15, q = l >> 4;
    const unsigned short* bgl = Badj + (long)f0*(11*2*BFRAG_F16) + (unsigned)l*8;

    #pragma unroll 1
    for (int k = 0; k < 6; k++){
        int buf = k & 1;
        __syncthreads();   // drains vmcnt -> vt[buf] complete; prior readers of [buf^1] done
        if (k + 1 < 6){    // async-stage next channel into the other buffer
            #pragma unroll
            for (int r = 0; r < 5; r++){
                if (act[r]) gl_lds16(gsrc[r] + (long)VPLANE, &vt[buf^1][0] + lofs[r]);
                gsrc[r] += VPLANE;
            }
        }
        // A byte offset: (16w + m15 + ky)*112 + sb*32 + q*16 ; comp i adds AC_COMP_BYTES
        const char* va = &vt[buf][0] + (w*16 + m15)*112 + q*16;
        const unsigned short* bk = bgl + (long)k*(11*2*BFRAG_F16);
        #pragma unroll
        for (int ky = 0; ky < 11; ky++){
            union { v4i i; half8_t h; } br, bi;
            br.i = *(const v4i*)(bk + ky*(2*BFRAG_F16));
            bi.i = *(const v4i*)(bk + ky*(2*BFRAG_F16) + BFRAG_F16);
            const char* var = va + ky*112;
            #pragma unroll
            for (int sb = 0; sb < 2; sb++){
                union { v4i i; half8_t h; } ar, ai;
                ar.i = *(const v4i*)(var + sb*32);
                ai.i = *(const v4i*)(var + sb*32 + AC_COMP_BYTES);
                Drr[sb] = __builtin_amdgcn_mfma_f32_16x16x32_f16(ar.h, br.h, Drr[sb], 0, 0, 0);
                Dii[sb] = __builtin_amdgcn_mfma_f32_16x16x32_f16(ai.h, bi.h, Dii[sb], 0, 0, 0);
                Dir[sb] = __builtin_amdgcn_mfma_f32_16x16x32_f16(ai.h, br.h, Dir[sb], 0, 0, 0);
                Dri[sb] = __builtin_amdgcn_mfma_f32_16x16x32_f16(ar.h, bi.h, Dri[sb], 0, 0, 0);
            }
        }
    }

    // combine + store: all 16 n-cols valid per slab
    float2* out = rg + (long)part*NPIX + (long)t*HW;
    #pragma unroll
    for (int sb = 0; sb < 2; sb++){
        int x = X0 + 16*sb + m15;
        #pragma unroll
        for (int r = 0; r < 4; r++){
            int y = Y0 + w*16 + q*4 + r;
            out[(long)y*256 + x] = make_float2(Drr[sb][r] + Dii[sb][r],
                                               Dir[sb][r] - Dri[sb][r]);
        }
    }
}

// ---------------- fused data-consistency + momentum update + bf16 mirror --------
__global__ void dc_update_kernel(float2* __restrict__ Xpad, float2* __restrict__ m,
                                 const float2* __restrict__ rg, const float2* __restrict__ G,
                                 const float* __restrict__ mask, unsigned short* __restrict__ Xbf,
                                 const float* __restrict__ alphas, const float* __restrict__ moms,
                                 int l){
    __shared__ float2 lds[2][256];
    __shared__ float2 tw[128];
    int tid = threadIdx.x;
    int line = tid >> 7;
    int j = tid & 127;
    if (tid < 128){
        float s, c;
        sincosf(6.283185307179586f * (float)tid / 256.0f, &s, &c);
        tw[tid] = make_float2(c, s);
    }
    long gl = (long)blockIdx.x*2 + line;
    int t = (int)(gl >> 8);
    int h = (int)(gl & 255);
    float2* src = Xpad + (long)t*VPLANE + VIOFF + (long)h*VSTRIDE;
    float2 xo0, xo1;
    {
        float sg = (j & 1) ? -1.f : 1.f;
        xo0 = src[j]; xo1 = src[j+128];
        lds[line][j]     = make_float2(xo0.x*sg, xo0.y*sg);
        lds[line][j+128] = make_float2(xo1.x*sg, xo1.y*sg);
    }
    __syncthreads();
    for (int s = 0; s < 8; s++){
        int half = 128 >> s;
        int pos = j & (half-1);
        int grp = j >> (7-s);
        int i0 = (grp << (8-s)) + pos;
        int i1 = i0 + half;
        float2 u = lds[line][i0], v = lds[line][i1];
        float2 w = tw[pos << s]; w.y = -w.y;
        lds[line][i0] = make_float2(u.x+v.x, u.y+v.y);
        float2 d = make_float2(u.x-v.x, u.y-v.y);
        lds[line][i1] = cmulf(d, w);
        __syncthreads();
    }
    {
        int k1 = __brev((unsigned)j) >> 24;
        int k2 = __brev((unsigned)(j+128)) >> 24;
        float mv1 = mask[t*256 + k1] * (1.0f/256.0f);
        float mv2 = mask[t*256 + k2] * (1.0f/256.0f);
        float2 a = lds[line][j], b = lds[line][j+128];
        lds[line][j]     = make_float2(a.x*mv1, a.y*mv1);
        lds[line][j+128] = make_float2(b.x*mv2, b.y*mv2);
    }
    __syncthreads();
    for (int s = 0; s < 8; s++){
        int m2 = 1 << s;
        int pos = j & (m2-1);
        int grp = j >> s;
        int i0 = (grp << (s+1)) + pos;
        int i1 = i0 + m2;
        float2 u = lds[line][i0];
        float2 v = cmulf(lds[line][i1], tw[pos << (7-s)]);
        lds[line][i0] = make_float2(u.x+v.x, u.y+v.y);
        lds[line][i1] = make_float2(u.x-v.x, u.y-v.y);
        __syncthreads();
    }
    float a  = alphas[l];
    float mu = moms[l];
    float sg = (j & 1) ? -1.f : 1.f;
    #pragma unroll
    for (int half = 0; half < 2; half++){
        int k = j + half*128;
        long idx = gl*256 + k;
        float2 d = lds[line][k];
        d = make_float2(d.x*sg, d.y*sg);
        float2 g = G[idx];
        float rx = 0.f, ry = 0.f;
        #pragma unroll
        for (int p = 0; p < ADJ_PARTS; p++){
            float2 r = rg[idx + (long)p*NPIX];
            rx += r.x; ry += r.y;
        }
        float2 grad = make_float2(fmaf(a, d.x - g.x, rx), fmaf(a, d.y - g.y, ry));
        float2 mm;
        if (l == 0){
            mm = grad;
        } else {
            float2 mv = m[idx];
            mm = make_float2(fmaf(mu, mv.x, grad.x), fmaf(mu, mv.y, grad.y));
        }
        m[idx] = mm;
        float2 xo = half ? xo1 : xo0;
        float2 nv = make_float2(xo.x - mm.x, xo.y - mm.y);
        src[k] = nv;
        long off = VIOFF + (long)h*VSTRIDE + k;
        unsigned short vr = f2bf(nv.x), vi = f2bf(nv.y);
        Xbf[((long)(0*6+t))*VPLANE + off]     = vr;
        Xbf[((long)(1*6+t))*VPLANE + off]     = vi;
        Xbf[((long)(2*6+t))*VPLANE + off - 1] = vr;
        Xbf[((long)(3*6+t))*VPLANE + off - 1] = vi;
    }
}

// ---------------- output: stack(real, imag)*norm ----------------
__global__ void output_kernel(const float2* __restrict__ Xpad, const float* __restrict__ sums,
                              float* __restrict__ out){
    int i = blockIdx.x*256 + threadIdx.x;
    int t = i >> 16;
    int p = i & 65535;
    int h = p >> 8, w = p & 255;
    float norm = sqrtf(sums[0]/sums[1]);
    float2 v = Xpad[(long)t*VPLANE + VIOFF + h*VSTRIDE + w];
    out[2*i]   = v.x * norm;
    out[2*i+1] = v.y * norm;
}

extern "C" void kernel_launch(void* const* d_in, const int* in_sizes, int n_in,
                              void* d_out, int out_size, void* d_ws, size_t ws_size,
                              hipStream_t stream){
    const float* Xr    = (const float*)d_in[0];
    const float* Xi    = (const float*)d_in[1];
    const float* mask  = (const float*)d_in[2];
    const float* kr    = (const float*)d_in[3];
    const float* ki    = (const float*)d_in[4];
    const float* knots = (const float*)d_in[5];
    const float* alph  = (const float*)d_in[6];
    const float* moms  = (const float*)d_in[7];
    const float* k0    = (const float*)d_in[8];

    float* ws   = (float*)d_ws;
    float* sums = ws;                                          // 16 floats
    unsigned int*   Wd  = (unsigned int*)(ws + 16);            // legacy slot
    unsigned short* Wq  = (unsigned short*)(Wd + 8*WD_PER_LAYER);  // 8*16896 bf16
    unsigned short* Xbf = Wq + 8*WQ_PER_LAYER;                 // 24*VPLANE bf16
    float2* mbuf = (float2*)(Xbf + 24*VPLANE);
    float2* G    = mbuf + NPIX;
    float2* rg   = G    + NPIX;                                // NPARTS*NPIX; [0] also init tmp
    float2* Xpad = rg   + NPARTS*NPIX;                         // 6*VPLANE float2
    unsigned short* Vp = (unsigned short*)(Xpad + TT*VPLANE);  // 288*VPLANE ushort (f16)
    float2* Xks  = (float2*)Vp;                                // init-only alias
    unsigned short* Badj = Vp + (size_t)NPLANES2*VPLANE;       // adj B-frags (4.3 MB)

    const float OS = 1.0f/16.0f;

    hipMemsetAsync(sums, 0, 2*sizeof(float), stream);
    hipMemsetAsync(Xbf, 0, (size_t)24*VPLANE*sizeof(unsigned short), stream);  // bf16 halos

    prepack_wfrag_kernel<<<(8*WQ_PER_LAYER + 255)/256, 256, 0, stream>>>(kr, ki, Wq);
    prepack_badj_kernel<<<(8*BADJ_PER_LAYER_F16 + 255)/256, 256, 0, stream>>>(kr, ki, Badj);
    reduce_kernel<<<384, 256, 0, stream>>>(Xr, Xi, mask, sums);
    normalize_kernel<<<NPIX/256, 256, 0, stream>>>(Xr, Xi, sums, Xks);

    // init: Xpad = k2i(Xks)*k0 (padded, + bf16 mirror) ; G = k2i(Xks)
    fft_row_kernel<<<TT*128, 256, 0, stream>>>(Xks, rg, +1.0f, OS);
    fft_col_kernel<<<TT*(256/CPB), 256, 0, stream>>>(rg, Xpad, G, Xbf, +1.0f, OS, k0);

    // zero halos AFTER init (Xks alias in Vp region is dead now)
    halo_zero_all_kernel<<<((TT+NPLANES2)*HALO_PER_PLANE + 255)/256, 256, 0, stream>>>(Xpad, Vp);

    for (int l = 0; l < 8; l++){
        conv_fwd_mfma_kernel<<<dim3(4*256,1,1), 256, 0, stream>>>(
            Xbf, Wq + (long)l*WQ_PER_LAYER, knots + (long)l*KN*FC, Vp);
        conv_adj_mfma_kernel<<<dim3(8*4*ADJ_PARTS*TT,1,1), 256, 0, stream>>>(
            Vp, Badj + (long)l*BADJ_PER_LAYER_F16, rg);
        dc_update_kernel<<<TT*128, 256, 0, stream>>>(Xpad, mbuf, rg, G, mask, Xbf, alph, moms, l);
    }

    output_kernel<<<NPIX/256, 256, 0, stream>>>(Xpad, sums, (float*)d_out);
}